// Round 4
// baseline (8318.712 us; speedup 1.0000x reference)
//
#include <hip/hip_runtime.h>

#define B_    512
#define L_    16
#define IN_   128
#define H_    1024
#define T_    64
#define OUTROW 10240   /* (L_+T_)*IN_ */

typedef __attribute__((ext_vector_type(8))) short bf8;
typedef __attribute__((ext_vector_type(4))) float f4;
typedef unsigned short u16;
typedef unsigned int   u32;

#define MFMA16(a, b, c) __builtin_amdgcn_mfma_f32_16x16x32_bf16(a, b, c, 0, 0, 0)

__device__ __forceinline__ u16 f2bf(float f) {
    u32 u = __builtin_bit_cast(u32, f);
    u32 r = (u + 0x7fffu + ((u >> 16) & 1u)) >> 16;
    return (u16)r;
}
__device__ __forceinline__ float sigm(float x) { return 1.f / (1.f + __expf(-x)); }
__device__ __forceinline__ float tanh_f(float x) {
    float ax = fabsf(x);
    float e = __expf(-2.f * ax);
    float t = (1.f - e) / (1.f + e);
    return x < 0.f ? -t : t;
}
__device__ __forceinline__ bf8 ld8(const u16* p) { return *(const bf8*)p; }

// Direct-register K-segment: acc[4][4] += A_seg * B_seg^T over NK 64-wide K-tiles.
// Fragments loaded straight global->VGPR (each lane's frag = contiguous 16B; a
// wave-load touches 16 fully-consumed 64B lines). No LDS, no barriers -> compiler
// freely pipelines tile k+1 loads over tile k MFMAs.
// Requires in scope: ap[4] (A row ptrs, already + qd*8), bp[4], acc, KB0 = B-side
// k-offset of this segment's start (elements).
#define GEMM_SEG(NK, KB0)                                                   \
  _Pragma("unroll 2")                                                       \
  for (int kt_ = 0; kt_ < (NK); ++kt_) {                                    \
    _Pragma("unroll")                                                       \
    for (int s_ = 0; s_ < 2; ++s_) {                                        \
      const int ka_ = kt_ * 64 + s_ * 32;                                   \
      const int kb_ = (KB0) + ka_;                                          \
      bf8 a_[4], b_[4];                                                     \
      _Pragma("unroll")                                                     \
      for (int g_ = 0; g_ < 4; ++g_) a_[g_] = ld8(ap[g_] + ka_);            \
      _Pragma("unroll")                                                     \
      for (int g_ = 0; g_ < 4; ++g_) b_[g_] = ld8(bp[g_] + kb_);            \
      _Pragma("unroll")                                                     \
      for (int g_ = 0; g_ < 4; ++g_) {                                      \
        _Pragma("unroll")                                                   \
        for (int t_ = 0; t_ < 4; ++t_)                                      \
          acc[g_][t_] = MFMA16(a_[g_], b_[t_], acc[g_][t_]);                \
      }                                                                     \
    }                                                                       \
  }

// ---- LSTM layer: GEMM over concat(A0, A1) + fused cell epilogue.
// Weight rows permuted p = (u>>4)*64 + G*16 + (u&15); a block's 64-col group =
// gates i,f,g,o (acc col-tiles 0..3) of units u = tn*16 + l15 -- all in-lane.
__global__ __launch_bounds__(64, 1) void cell_gemm(
    const u16* __restrict__ pA0, int ldA0, int nk1,
    const u16* __restrict__ pA1, int ldA1, int nk2,
    const u16* __restrict__ pB, int Ktot,
    const float* __restrict__ bias, float* __restrict__ Cst, u16* __restrict__ Hdst)
{
    const int tn = blockIdx.x, tm = blockIdx.y;
    const int lane = threadIdx.x & 63;
    const int l15 = lane & 15, qd = lane >> 4;

    f4 acc[4][4];
#pragma unroll
    for (int i = 0; i < 4; ++i)
#pragma unroll
        for (int j = 0; j < 4; ++j) acc[i][j] = (f4)(0.f);

    const u16* bp[4];
#pragma unroll
    for (int t = 0; t < 4; ++t)
        bp[t] = pB + (size_t)(tn * 64 + t * 16 + l15) * Ktot + qd * 8;

    {
        const u16* ap[4];
#pragma unroll
        for (int g = 0; g < 4; ++g)
            ap[g] = pA0 + (size_t)(tm * 64 + g * 16 + l15) * ldA0 + qd * 8;
        GEMM_SEG(nk1, 0)
    }
    {
        const u16* ap[4];
#pragma unroll
        for (int g = 0; g < 4; ++g)
            ap[g] = pA1 + (size_t)(tm * 64 + g * 16 + l15) * ldA1 + qd * 8;
        const int kbase = nk1 * 64;
        GEMM_SEG(nk2, kbase)
    }

    const int u  = tn * 16 + l15;
    const int cb = tn * 64 + l15;
    const float bi = bias[cb],      bf_ = bias[cb + 16];
    const float bg = bias[cb + 32], bo  = bias[cb + 48];
#pragma unroll
    for (int rg = 0; rg < 4; ++rg) {
#pragma unroll
        for (int r = 0; r < 4; ++r) {
            const int row = tm * 64 + rg * 16 + qd * 4 + r;
            const float I  = sigm(acc[rg][0][r] + bi);
            const float F  = sigm(acc[rg][1][r] + bf_);
            const float Gg = tanh_f(acc[rg][2][r] + bg);
            const float O  = sigm(acc[rg][3][r] + bo);
            const size_t ix = (size_t)row * H_ + u;
            const float cn = F * Cst[ix] + I * Gg;
            Cst[ix] = cn;
            Hdst[ix] = f2bf(O * tanh_f(cn));
        }
    }
}

// ---- Output projection, fully fused: xl = xin + h1 @ Wout^T + b_out.
// Grid (2, 8) = 16 blocks. Writes XL (fp32), XLbf (bf16 -> next L0), dout slot.
__global__ __launch_bounds__(64, 1) void proj_gemm(
    const u16* __restrict__ pA,   // H1 [512 x 1024] bf16
    const u16* __restrict__ pB,   // Woutb [128 x 1024] bf16
    const float* __restrict__ bout,
    const float* __restrict__ xin, int ldxin,
    float* __restrict__ XL, u16* __restrict__ XLbf,
    float* __restrict__ dout, int slot)
{
    const int tn = blockIdx.x, tm = blockIdx.y;
    const int lane = threadIdx.x & 63;
    const int l15 = lane & 15, qd = lane >> 4;

    f4 acc[4][4];
#pragma unroll
    for (int i = 0; i < 4; ++i)
#pragma unroll
        for (int j = 0; j < 4; ++j) acc[i][j] = (f4)(0.f);

    const u16* bp[4];
#pragma unroll
    for (int t = 0; t < 4; ++t)
        bp[t] = pB + (size_t)(tn * 64 + t * 16 + l15) * H_ + qd * 8;
    const u16* ap[4];
#pragma unroll
    for (int g = 0; g < 4; ++g)
        ap[g] = pA + (size_t)(tm * 64 + g * 16 + l15) * H_ + qd * 8;
    GEMM_SEG(16, 0)

#pragma unroll
    for (int t = 0; t < 4; ++t) {
        const int col = tn * 64 + t * 16 + l15;
        const float bo = bout[col];
#pragma unroll
        for (int rg = 0; rg < 4; ++rg)
#pragma unroll
            for (int r = 0; r < 4; ++r) {
                const int row = tm * 64 + rg * 16 + qd * 4 + r;
                const float v = xin[(size_t)row * ldxin + col] + acc[rg][t][r] + bo;
                XL[row * IN_ + col] = v;
                XLbf[row * IN_ + col] = f2bf(v);
                dout[(size_t)row * OUTROW + slot * IN_ + col] = v;
            }
    }
}

// ---- Weight conversion: fp32 -> bf16, gate-permuted rows, fused biases ----
__global__ void conv_w(const float* Wih0, const float* Whh0, const float* bih0, const float* bhh0,
                       const float* Wih1, const float* Whh1, const float* bih1, const float* bhh1,
                       const float* Wout,
                       u16* W0c, float* b0p, u16* W1c, float* b1p, u16* Woutb)
{
    const int bid = blockIdx.x, tid = threadIdx.x;
    if (bid < 4096) {
        const int p = bid, rem = p & 63, G = rem >> 4, u = (p >> 6) * 16 + (rem & 15);
        const int src = G * H_ + u;
        for (int j = tid; j < IN_; j += 256)
            W0c[(size_t)p * 1152 + j] = f2bf(Wih0[(size_t)src * IN_ + j]);
        for (int j = tid; j < H_; j += 256)
            W0c[(size_t)p * 1152 + 128 + j] = f2bf(Whh0[(size_t)src * H_ + j]);
        if (tid == 0) b0p[p] = bih0[src] + bhh0[src];
    } else if (bid < 8192) {
        const int p = bid - 4096, rem = p & 63, G = rem >> 4, u = (p >> 6) * 16 + (rem & 15);
        const int src = G * H_ + u;
        for (int j = tid; j < H_; j += 256) {
            W1c[(size_t)p * 2048 + j]        = f2bf(Wih1[(size_t)src * H_ + j]);
            W1c[(size_t)p * 2048 + 1024 + j] = f2bf(Whh1[(size_t)src * H_ + j]);
        }
        if (tid == 0) b1p[p] = bih1[src] + bhh1[src];
    } else {
        const int r = bid - 8192; // 0..127
        for (int j = tid; j < H_; j += 256)
            Woutb[(size_t)r * H_ + j] = f2bf(Wout[(size_t)r * H_ + j]);
    }
}

// ---- Setup: zero states, x -> bf16 staging, x -> out[:, 0:16] copy ----
__global__ void setup_k(const float* __restrict__ x, u16* __restrict__ Xb,
                        u16* H0, u16* H1, float* c0, float* c1,
                        float* __restrict__ dout)
{
    const int i = blockIdx.x * 256 + threadIdx.x;  // < 512*16*128 = 1048576
    const float v = x[i];
    Xb[i] = f2bf(v);
    dout[(size_t)(i >> 11) * OUTROW + (i & 2047)] = v;
    if (i < B_ * H_) { H0[i] = 0; H1[i] = 0; c0[i] = 0.f; c1[i] = 0.f; }
}

extern "C" void kernel_launch(void* const* d_in, const int* in_sizes, int n_in,
                              void* d_out, int out_size, void* d_ws, size_t ws_size,
                              hipStream_t stream)
{
    const float* x    = (const float*)d_in[0];
    const float* Wih0 = (const float*)d_in[1];
    const float* Whh0 = (const float*)d_in[2];
    const float* bih0 = (const float*)d_in[3];
    const float* bhh0 = (const float*)d_in[4];
    const float* Wih1 = (const float*)d_in[5];
    const float* Whh1 = (const float*)d_in[6];
    const float* bih1 = (const float*)d_in[7];
    const float* bhh1 = (const float*)d_in[8];
    const float* Wout = (const float*)d_in[9];
    const float* bout = (const float*)d_in[10];
    float* dout = (float*)d_out;

    char* ws = (char*)d_ws;
    size_t off = 0;
    auto alloc = [&](size_t bytes) -> char* {
        char* p = ws + off; off += (bytes + 255) & ~(size_t)255; return p;
    };
    u16*  W0c   = (u16*)alloc(4096 * 1152 * 2);
    u16*  W1c   = (u16*)alloc(4096 * 2048 * 2);
    u16*  Woutb = (u16*)alloc(128 * 1024 * 2);
    float* b0p  = (float*)alloc(4096 * 4);
    float* b1p  = (float*)alloc(4096 * 4);
    u16*  Xb    = (u16*)alloc((size_t)B_ * L_ * IN_ * 2);
    u16*  H0b[2]; H0b[0] = (u16*)alloc((size_t)B_ * H_ * 2); H0b[1] = (u16*)alloc((size_t)B_ * H_ * 2);
    u16*  H1b[2]; H1b[0] = (u16*)alloc((size_t)B_ * H_ * 2); H1b[1] = (u16*)alloc((size_t)B_ * H_ * 2);
    float* c0   = (float*)alloc((size_t)B_ * H_ * 4);
    float* c1   = (float*)alloc((size_t)B_ * H_ * 4);
    float* XL   = (float*)alloc((size_t)B_ * IN_ * 4);
    u16*  XLbf  = (u16*)alloc((size_t)B_ * IN_ * 2);

    conv_w<<<8320, 256, 0, stream>>>(Wih0, Whh0, bih0, bhh0,
                                     Wih1, Whh1, bih1, bhh1, Wout,
                                     W0c, b0p, W1c, b1p, Woutb);
    setup_k<<<4096, 256, 0, stream>>>(x, Xb, H0b[0], H1b[0], c0, c1, dout);

    const dim3 cgrid(64, 8), pgrid(2, 8);
    int p = 0;
    for (int g = 0; g < 79; ++g) {   // 16 prompt + 63 rollout stack steps
        const u16* xpart; int ldx;
        if (g < 16) { xpart = Xb + g * IN_; ldx = L_ * IN_; }
        else        { xpart = XLbf;         ldx = IN_; }
        cell_gemm<<<cgrid, 64, 0, stream>>>(xpart, ldx, 2, H0b[p], H_, 16,
                                            W0c, IN_ + H_, b0p, c0, H0b[1 - p]);
        cell_gemm<<<cgrid, 64, 0, stream>>>(H0b[1 - p], H_, 16, H1b[p], H_, 16,
                                            W1c, 2 * H_, b1p, c1, H1b[1 - p]);
        if (g >= 15) {
            const int s = g - 15;            // 0..63 -> out slot 16+s
            const float* xin; int ldxin;
            if (s == 0) { xin = x + 15 * IN_; ldxin = L_ * IN_; }
            else        { xin = XL;           ldxin = IN_; }
            proj_gemm<<<pgrid, 64, 0, stream>>>(H1b[1 - p], Woutb, bout,
                                                xin, ldxin, XL, XLbf, dout, 16 + s);
        }
        p ^= 1;
    }
}

// Round 5
// 5333.887 us; speedup vs baseline: 1.5596x; 1.5596x over previous
//
#include <hip/hip_runtime.h>

#define B_    512
#define L_    16
#define IN_   128
#define H_    1024
#define T_    64
#define OUTROW 10240   /* (L_+T_)*IN_ */

typedef __attribute__((ext_vector_type(8))) short bf8;
typedef __attribute__((ext_vector_type(4))) float f4;
typedef unsigned short u16;
typedef unsigned int   u32;

#define MFMA16(a, b, c) __builtin_amdgcn_mfma_f32_16x16x32_bf16(a, b, c, 0, 0, 0)

__device__ __forceinline__ u16 f2bf(float f) {
    u32 u = __builtin_bit_cast(u32, f);
    u32 r = (u + 0x7fffu + ((u >> 16) & 1u)) >> 16;
    return (u16)r;
}
__device__ __forceinline__ float sigm(float x) { return 1.f / (1.f + __expf(-x)); }
__device__ __forceinline__ float tanh_f(float x) {
    float ax = fabsf(x);
    float e = __expf(-2.f * ax);
    float t = (1.f - e) / (1.f + e);
    return x < 0.f ? -t : t;
}
__device__ __forceinline__ bf8 ld8(const u16* p) { return *(const bf8*)p; }

#define RSTRIDE 65   /* padded fp32 row stride in LDS reduction buffer */

// ---- LSTM layer: 4-wave split-K GEMM + LDS reduction + fused cell epilogue.
// Block = 256 threads (4 waves), each wave owns K-tiles kt === ws (mod 4) and a
// full 64x64 fp32 accumulator; partials summed through padded LDS. Grid (64,8)
// = 512 blocks = 2 blocks/CU -> 8 waves/CU (2/SIMD: all SIMDs fed).
// A = concat(A0 [nk1 tiles], A1 [nk2 tiles]); B rows gate-permuted
// p = (u>>4)*64 + G*16 + (u&15): a block's 64-col group = gates i,f,g,o of
// units u = tn*16 + (0..15).
__global__ __launch_bounds__(256, 2) void cell_gemm(
    const u16* __restrict__ pA0, int ldA0, int nk1,
    const u16* __restrict__ pA1, int ldA1, int nk2,
    const u16* __restrict__ pB, int Ktot,
    const float* __restrict__ bias, float* __restrict__ Cst, u16* __restrict__ Hdst)
{
    __shared__ float red[4][64 * RSTRIDE];
    const int tn = blockIdx.x, tm = blockIdx.y;
    const int tid = threadIdx.x;
    const int lane = tid & 63, ws = tid >> 6;
    const int l15 = lane & 15, qd = lane >> 4;

    f4 acc[4][4];
#pragma unroll
    for (int i = 0; i < 4; ++i)
#pragma unroll
        for (int j = 0; j < 4; ++j) acc[i][j] = (f4)(0.f);

    const u16* bp[4];
#pragma unroll
    for (int t = 0; t < 4; ++t)
        bp[t] = pB + (size_t)(tn * 64 + t * 16 + l15) * Ktot + qd * 8;
    const u16* apx[4];
    const u16* aph[4];
#pragma unroll
    for (int g = 0; g < 4; ++g) {
        apx[g] = pA0 + (size_t)(tm * 64 + g * 16 + l15) * ldA0 + qd * 8;
        aph[g] = pA1 + (size_t)(tm * 64 + g * 16 + l15) * ldA1 + qd * 8;
    }

    const int nk = nk1 + nk2;
    for (int kt = ws; kt < nk; kt += 4) {
        const bool inx = kt < nk1;
        const int ko = (inx ? kt : kt - nk1) * 64;
        const int kb = kt * 64;
#pragma unroll
        for (int s = 0; s < 2; ++s) {
            bf8 a[4], b[4];
#pragma unroll
            for (int g = 0; g < 4; ++g) {
                const u16* base = inx ? apx[g] : aph[g];
                a[g] = ld8(base + ko + s * 32);
            }
#pragma unroll
            for (int t = 0; t < 4; ++t) b[t] = ld8(bp[t] + kb + s * 32);
#pragma unroll
            for (int g = 0; g < 4; ++g)
#pragma unroll
                for (int t = 0; t < 4; ++t)
                    acc[g][t] = MFMA16(a[g], b[t], acc[g][t]);
        }
    }

    // dump partials to padded LDS
#pragma unroll
    for (int rg = 0; rg < 4; ++rg)
#pragma unroll
        for (int t = 0; t < 4; ++t)
#pragma unroll
            for (int r = 0; r < 4; ++r)
                red[ws][(rg * 16 + qd * 4 + r) * RSTRIDE + t * 16 + l15] = acc[rg][t][r];
    __syncthreads();

    // distributed epilogue: wave ws handles rows ws*16..ws*16+15 of the tile;
    // lane -> row = ws*16 + (lane&15), units u15 = qd*4 + j (j=0..3)
    const int erow = ws * 16 + (lane & 15);
    const int grow = tm * 64 + erow;
#pragma unroll
    for (int j = 0; j < 4; ++j) {
        const int u15 = qd * 4 + j;
        float g4[4];
#pragma unroll
        for (int G = 0; G < 4; ++G) {
            float s = red[0][erow * RSTRIDE + G * 16 + u15];
#pragma unroll
            for (int w = 1; w < 4; ++w) s += red[w][erow * RSTRIDE + G * 16 + u15];
            g4[G] = s + bias[tn * 64 + G * 16 + u15];
        }
        const float I  = sigm(g4[0]);
        const float F  = sigm(g4[1]);
        const float Gg = tanh_f(g4[2]);
        const float O  = sigm(g4[3]);
        const size_t ix = (size_t)grow * H_ + tn * 16 + u15;
        const float cn = F * Cst[ix] + I * Gg;
        Cst[ix] = cn;
        Hdst[ix] = f2bf(O * tanh_f(cn));
    }
}

// ---- Output projection: 4-wave split-K (K=1024, 4 tiles/wave) + fused epilogue.
// xl = xin + h1 @ Wout^T + b_out; writes XL (fp32), XLbf (bf16), dout slot.
__global__ __launch_bounds__(256, 2) void proj_gemm(
    const u16* __restrict__ pA,   // H1 [512 x 1024] bf16
    const u16* __restrict__ pB,   // Woutb [128 x 1024] bf16
    const float* __restrict__ bout,
    const float* __restrict__ xin, int ldxin,
    float* __restrict__ XL, u16* __restrict__ XLbf,
    float* __restrict__ dout, int slot)
{
    __shared__ float red[4][64 * RSTRIDE];
    const int tn = blockIdx.x, tm = blockIdx.y;
    const int tid = threadIdx.x;
    const int lane = tid & 63, ws = tid >> 6;
    const int l15 = lane & 15, qd = lane >> 4;

    f4 acc[4][4];
#pragma unroll
    for (int i = 0; i < 4; ++i)
#pragma unroll
        for (int j = 0; j < 4; ++j) acc[i][j] = (f4)(0.f);

    const u16* bp[4];
#pragma unroll
    for (int t = 0; t < 4; ++t)
        bp[t] = pB + (size_t)(tn * 64 + t * 16 + l15) * H_ + qd * 8;
    const u16* ap[4];
#pragma unroll
    for (int g = 0; g < 4; ++g)
        ap[g] = pA + (size_t)(tm * 64 + g * 16 + l15) * H_ + qd * 8;

    for (int kt = ws; kt < 16; kt += 4) {
        const int kb = kt * 64;
#pragma unroll
        for (int s = 0; s < 2; ++s) {
            bf8 a[4], b[4];
#pragma unroll
            for (int g = 0; g < 4; ++g) a[g] = ld8(ap[g] + kb + s * 32);
#pragma unroll
            for (int t = 0; t < 4; ++t) b[t] = ld8(bp[t] + kb + s * 32);
#pragma unroll
            for (int g = 0; g < 4; ++g)
#pragma unroll
                for (int t = 0; t < 4; ++t)
                    acc[g][t] = MFMA16(a[g], b[t], acc[g][t]);
        }
    }

#pragma unroll
    for (int rg = 0; rg < 4; ++rg)
#pragma unroll
        for (int t = 0; t < 4; ++t)
#pragma unroll
            for (int r = 0; r < 4; ++r)
                red[ws][(rg * 16 + qd * 4 + r) * RSTRIDE + t * 16 + l15] = acc[rg][t][r];
    __syncthreads();

    // epilogue: wave ws -> rows ws*16+(lane&15); lane covers cols qd*16 + j, j=0..15
    const int erow = ws * 16 + (lane & 15);
    const int grow = tm * 64 + erow;
#pragma unroll
    for (int j = 0; j < 16; ++j) {
        const int cin = qd * 16 + j;
        const int col = tn * 64 + cin;
        float s = red[0][erow * RSTRIDE + cin];
#pragma unroll
        for (int w = 1; w < 4; ++w) s += red[w][erow * RSTRIDE + cin];
        const float v = xin[(size_t)grow * ldxin + col] + s + bout[col];
        XL[grow * IN_ + col] = v;
        XLbf[grow * IN_ + col] = f2bf(v);
        dout[(size_t)grow * OUTROW + slot * IN_ + col] = v;
    }
}

// ---- Weight conversion: fp32 -> bf16, gate-permuted rows, fused biases ----
__global__ void conv_w(const float* Wih0, const float* Whh0, const float* bih0, const float* bhh0,
                       const float* Wih1, const float* Whh1, const float* bih1, const float* bhh1,
                       const float* Wout,
                       u16* W0c, float* b0p, u16* W1c, float* b1p, u16* Woutb)
{
    const int bid = blockIdx.x, tid = threadIdx.x;
    if (bid < 4096) {
        const int p = bid, rem = p & 63, G = rem >> 4, u = (p >> 6) * 16 + (rem & 15);
        const int src = G * H_ + u;
        for (int j = tid; j < IN_; j += 256)
            W0c[(size_t)p * 1152 + j] = f2bf(Wih0[(size_t)src * IN_ + j]);
        for (int j = tid; j < H_; j += 256)
            W0c[(size_t)p * 1152 + 128 + j] = f2bf(Whh0[(size_t)src * H_ + j]);
        if (tid == 0) b0p[p] = bih0[src] + bhh0[src];
    } else if (bid < 8192) {
        const int p = bid - 4096, rem = p & 63, G = rem >> 4, u = (p >> 6) * 16 + (rem & 15);
        const int src = G * H_ + u;
        for (int j = tid; j < H_; j += 256) {
            W1c[(size_t)p * 2048 + j]        = f2bf(Wih1[(size_t)src * H_ + j]);
            W1c[(size_t)p * 2048 + 1024 + j] = f2bf(Whh1[(size_t)src * H_ + j]);
        }
        if (tid == 0) b1p[p] = bih1[src] + bhh1[src];
    } else {
        const int r = bid - 8192; // 0..127
        for (int j = tid; j < H_; j += 256)
            Woutb[(size_t)r * H_ + j] = f2bf(Wout[(size_t)r * H_ + j]);
    }
}

// ---- Setup: zero states, x -> bf16 staging, x -> out[:, 0:16] copy ----
__global__ void setup_k(const float* __restrict__ x, u16* __restrict__ Xb,
                        u16* H0, u16* H1, float* c0, float* c1,
                        float* __restrict__ dout)
{
    const int i = blockIdx.x * 256 + threadIdx.x;  // < 512*16*128 = 1048576
    const float v = x[i];
    Xb[i] = f2bf(v);
    dout[(size_t)(i >> 11) * OUTROW + (i & 2047)] = v;
    if (i < B_ * H_) { H0[i] = 0; H1[i] = 0; c0[i] = 0.f; c1[i] = 0.f; }
}

extern "C" void kernel_launch(void* const* d_in, const int* in_sizes, int n_in,
                              void* d_out, int out_size, void* d_ws, size_t ws_size,
                              hipStream_t stream)
{
    const float* x    = (const float*)d_in[0];
    const float* Wih0 = (const float*)d_in[1];
    const float* Whh0 = (const float*)d_in[2];
    const float* bih0 = (const float*)d_in[3];
    const float* bhh0 = (const float*)d_in[4];
    const float* Wih1 = (const float*)d_in[5];
    const float* Whh1 = (const float*)d_in[6];
    const float* bih1 = (const float*)d_in[7];
    const float* bhh1 = (const float*)d_in[8];
    const float* Wout = (const float*)d_in[9];
    const float* bout = (const float*)d_in[10];
    float* dout = (float*)d_out;

    char* ws = (char*)d_ws;
    size_t off = 0;
    auto alloc = [&](size_t bytes) -> char* {
        char* p = ws + off; off += (bytes + 255) & ~(size_t)255; return p;
    };
    u16*  W0c   = (u16*)alloc(4096 * 1152 * 2);
    u16*  W1c   = (u16*)alloc(4096 * 2048 * 2);
    u16*  Woutb = (u16*)alloc(128 * 1024 * 2);
    float* b0p  = (float*)alloc(4096 * 4);
    float* b1p  = (float*)alloc(4096 * 4);
    u16*  Xb    = (u16*)alloc((size_t)B_ * L_ * IN_ * 2);
    u16*  H0b[2]; H0b[0] = (u16*)alloc((size_t)B_ * H_ * 2); H0b[1] = (u16*)alloc((size_t)B_ * H_ * 2);
    u16*  H1b[2]; H1b[0] = (u16*)alloc((size_t)B_ * H_ * 2); H1b[1] = (u16*)alloc((size_t)B_ * H_ * 2);
    float* c0   = (float*)alloc((size_t)B_ * H_ * 4);
    float* c1   = (float*)alloc((size_t)B_ * H_ * 4);
    float* XL   = (float*)alloc((size_t)B_ * IN_ * 4);
    u16*  XLbf  = (u16*)alloc((size_t)B_ * IN_ * 2);

    conv_w<<<8320, 256, 0, stream>>>(Wih0, Whh0, bih0, bhh0,
                                     Wih1, Whh1, bih1, bhh1, Wout,
                                     W0c, b0p, W1c, b1p, Woutb);
    setup_k<<<4096, 256, 0, stream>>>(x, Xb, H0b[0], H1b[0], c0, c1, dout);

    const dim3 cgrid(64, 8), pgrid(2, 8);
    int p = 0;
    for (int g = 0; g < 79; ++g) {   // 16 prompt + 63 rollout stack steps
        const u16* xpart; int ldx;
        if (g < 16) { xpart = Xb + g * IN_; ldx = L_ * IN_; }
        else        { xpart = XLbf;         ldx = IN_; }
        cell_gemm<<<cgrid, 256, 0, stream>>>(xpart, ldx, 2, H0b[p], H_, 16,
                                             W0c, IN_ + H_, b0p, c0, H0b[1 - p]);
        cell_gemm<<<cgrid, 256, 0, stream>>>(H0b[1 - p], H_, 16, H1b[p], H_, 16,
                                             W1c, 2 * H_, b1p, c1, H1b[1 - p]);
        if (g >= 15) {
            const int s = g - 15;            // 0..63 -> out slot 16+s
            const float* xin; int ldxin;
            if (s == 0) { xin = x + 15 * IN_; ldxin = L_ * IN_; }
            else        { xin = XL;           ldxin = IN_; }
            proj_gemm<<<pgrid, 256, 0, stream>>>(H1b[1 - p], Woutb, bout,
                                                 xin, ldxin, XL, XLbf, dout, 16 + s);
        }
        p ^= 1;
    }
}

// Round 6
// 5172.851 us; speedup vs baseline: 1.6081x; 1.0311x over previous
//
#include <hip/hip_runtime.h>

#define B_    512
#define L_    16
#define IN_   128
#define H_    1024
#define T_    64
#define OUTROW 10240   /* (L_+T_)*IN_ */

typedef __attribute__((ext_vector_type(8))) short bf8;
typedef __attribute__((ext_vector_type(4))) float f4;
typedef unsigned short u16;
typedef unsigned int   u32;

#define MFMA16(a, b, c) __builtin_amdgcn_mfma_f32_16x16x32_bf16(a, b, c, 0, 0, 0)

__device__ __forceinline__ u16 f2bf(float f) {
    u32 u = __builtin_bit_cast(u32, f);
    u32 r = (u + 0x7fffu + ((u >> 16) & 1u)) >> 16;
    return (u16)r;
}
__device__ __forceinline__ float sigm(float x) { return 1.f / (1.f + __expf(-x)); }
__device__ __forceinline__ float tanh_f(float x) {
    float ax = fabsf(x);
    float e = __expf(-2.f * ax);
    float t = (1.f - e) / (1.f + e);
    return x < 0.f ? -t : t;
}
__device__ __forceinline__ bf8 ld8(const u16* p) { return *(const bf8*)p; }

#define RSTRIDE 65   /* padded fp32 row stride in LDS reduction buffer */

// 16-MFMA pack on one fragment set (s-phase granularity)
#define MFMAP(AS, BS)                                                       \
  do {                                                                      \
    _Pragma("unroll")                                                       \
    for (int g_ = 0; g_ < 4; ++g_) {                                        \
      _Pragma("unroll")                                                     \
      for (int t_ = 0; t_ < 4; ++t_)                                        \
        acc[g_][t_] = MFMA16(AS[g_], BS[t_], acc[g_][t_]);                  \
    }                                                                       \
  } while (0)

// Load fragment set for phase PH of this wave's sequence.
// Phase -> (kt = ws + (PH>>1)*4, s = PH&1). A from concat(x-part, h-part).
#define LOADP_CELL(AS, BS, PH)                                              \
  do {                                                                      \
    const int kt_ = ws + (((PH) >> 1) << 2);                                \
    const int so_ = ((PH) & 1) * 32;                                        \
    const int kb_ = kt_ * 64 + so_;                                         \
    const bool ix_ = kt_ < nk1;                                             \
    const int ka_ = (ix_ ? kt_ : kt_ - nk1) * 64 + so_;                     \
    _Pragma("unroll")                                                       \
    for (int g_ = 0; g_ < 4; ++g_)                                          \
      AS[g_] = ld8((ix_ ? apx[g_] : aph[g_]) + ka_);                        \
    _Pragma("unroll")                                                       \
    for (int t_ = 0; t_ < 4; ++t_) BS[t_] = ld8(bp[t_] + kb_);              \
  } while (0)

#define LOADP_PROJ(AS, BS, PH)                                              \
  do {                                                                      \
    const int kt_ = ws + (((PH) >> 1) << 2);                                \
    const int k_  = kt_ * 64 + ((PH) & 1) * 32;                             \
    _Pragma("unroll")                                                       \
    for (int g_ = 0; g_ < 4; ++g_) AS[g_] = ld8(ap[g_] + k_);               \
    _Pragma("unroll")                                                       \
    for (int t_ = 0; t_ < 4; ++t_) BS[t_] = ld8(bp[t_] + k_);               \
  } while (0)

// ---- LSTM layer: 4-wave split-K GEMM (register-pipelined) + LDS reduction +
// fused cell epilogue. Block = 256 thr (4 waves); wave ws owns K-tiles
// kt === ws (mod 4); explicit 2-set register prefetch at s-phase granularity:
// phase p+1's 8 loads issue before phase p's 16 MFMAs (~512 shared SIMD cyc
// covers L2 latency). Grid (64,8) = 512 blocks = 2/CU -> 8 waves/CU.
// B rows gate-permuted p = (u>>4)*64 + G*16 + (u&15): block's 64-col group =
// gates i,f,g,o of units u = tn*16 + (0..15), all in-lane.
__global__ __launch_bounds__(256, 2) void cell_gemm(
    const u16* __restrict__ pA0, int ldA0, int nk1,
    const u16* __restrict__ pA1, int ldA1, int nk2,
    const u16* __restrict__ pB, int Ktot,
    const float* __restrict__ bias, float* __restrict__ Cst, u16* __restrict__ Hdst)
{
    __shared__ float red[4][64 * RSTRIDE];
    const int tn = blockIdx.x, tm = blockIdx.y;
    const int tid = threadIdx.x;
    const int lane = tid & 63, ws = tid >> 6;
    const int l15 = lane & 15, qd = lane >> 4;

    f4 acc[4][4];
#pragma unroll
    for (int i = 0; i < 4; ++i)
#pragma unroll
        for (int j = 0; j < 4; ++j) acc[i][j] = (f4)(0.f);

    const u16* bp[4];
#pragma unroll
    for (int t = 0; t < 4; ++t)
        bp[t] = pB + (size_t)(tn * 64 + t * 16 + l15) * Ktot + qd * 8;
    const u16* apx[4];
    const u16* aph[4];
#pragma unroll
    for (int g = 0; g < 4; ++g) {
        apx[g] = pA0 + (size_t)(tm * 64 + g * 16 + l15) * ldA0 + qd * 8;
        aph[g] = pA1 + (size_t)(tm * 64 + g * 16 + l15) * ldA1 + qd * 8;
    }

    const int nk  = nk1 + nk2;
    const int myn = (nk - ws + 3) >> 2;     // tiles for this wave
    const int nph = myn * 2;                // s-phases (always even)

    bf8 A0[4], B0[4], A1[4], B1[4];
    LOADP_CELL(A0, B0, 0);
    for (int ph = 0; ph < nph; ph += 2) {
        LOADP_CELL(A1, B1, ph + 1);
        MFMAP(A0, B0);
        if (ph + 2 < nph) LOADP_CELL(A0, B0, ph + 2);
        MFMAP(A1, B1);
    }

    // dump partials to padded LDS
#pragma unroll
    for (int rg = 0; rg < 4; ++rg)
#pragma unroll
        for (int t = 0; t < 4; ++t)
#pragma unroll
            for (int r = 0; r < 4; ++r)
                red[ws][(rg * 16 + qd * 4 + r) * RSTRIDE + t * 16 + l15] = acc[rg][t][r];
    __syncthreads();

    // distributed epilogue: wave ws -> rows ws*16+(lane&15); units u15 = qd*4+j
    const int erow = ws * 16 + (lane & 15);
    const int grow = tm * 64 + erow;
#pragma unroll
    for (int j = 0; j < 4; ++j) {
        const int u15 = qd * 4 + j;
        float g4[4];
#pragma unroll
        for (int G = 0; G < 4; ++G) {
            float s = red[0][erow * RSTRIDE + G * 16 + u15];
#pragma unroll
            for (int w = 1; w < 4; ++w) s += red[w][erow * RSTRIDE + G * 16 + u15];
            g4[G] = s + bias[tn * 64 + G * 16 + u15];
        }
        const float I  = sigm(g4[0]);
        const float F  = sigm(g4[1]);
        const float Gg = tanh_f(g4[2]);
        const float O  = sigm(g4[3]);
        const size_t ix = (size_t)grow * H_ + tn * 16 + u15;
        const float cn = F * Cst[ix] + I * Gg;
        Cst[ix] = cn;
        Hdst[ix] = f2bf(O * tanh_f(cn));
    }
}

// ---- Output projection: 4-wave split-K (register-pipelined) + fused epilogue.
// xl = xin + h1 @ Wout^T + b_out; writes XL (fp32), XLbf (bf16), dout slot.
__global__ __launch_bounds__(256, 2) void proj_gemm(
    const u16* __restrict__ pA,   // H1 [512 x 1024] bf16
    const u16* __restrict__ pB,   // Woutb [128 x 1024] bf16
    const float* __restrict__ bout,
    const float* __restrict__ xin, int ldxin,
    float* __restrict__ XL, u16* __restrict__ XLbf,
    float* __restrict__ dout, int slot)
{
    __shared__ float red[4][64 * RSTRIDE];
    const int tn = blockIdx.x, tm = blockIdx.y;
    const int tid = threadIdx.x;
    const int lane = tid & 63, ws = tid >> 6;
    const int l15 = lane & 15, qd = lane >> 4;

    f4 acc[4][4];
#pragma unroll
    for (int i = 0; i < 4; ++i)
#pragma unroll
        for (int j = 0; j < 4; ++j) acc[i][j] = (f4)(0.f);

    const u16* bp[4];
#pragma unroll
    for (int t = 0; t < 4; ++t)
        bp[t] = pB + (size_t)(tn * 64 + t * 16 + l15) * H_ + qd * 8;
    const u16* ap[4];
#pragma unroll
    for (int g = 0; g < 4; ++g)
        ap[g] = pA + (size_t)(tm * 64 + g * 16 + l15) * H_ + qd * 8;

    const int nph = 8;   // 16 K-tiles / 4 waves * 2 s-phases
    bf8 A0[4], B0[4], A1[4], B1[4];
    LOADP_PROJ(A0, B0, 0);
    for (int ph = 0; ph < nph; ph += 2) {
        LOADP_PROJ(A1, B1, ph + 1);
        MFMAP(A0, B0);
        if (ph + 2 < nph) LOADP_PROJ(A0, B0, ph + 2);
        MFMAP(A1, B1);
    }

#pragma unroll
    for (int rg = 0; rg < 4; ++rg)
#pragma unroll
        for (int t = 0; t < 4; ++t)
#pragma unroll
            for (int r = 0; r < 4; ++r)
                red[ws][(rg * 16 + qd * 4 + r) * RSTRIDE + t * 16 + l15] = acc[rg][t][r];
    __syncthreads();

    const int erow = ws * 16 + (lane & 15);
    const int grow = tm * 64 + erow;
#pragma unroll
    for (int j = 0; j < 16; ++j) {
        const int cin = qd * 16 + j;
        const int col = tn * 64 + cin;
        float s = red[0][erow * RSTRIDE + cin];
#pragma unroll
        for (int w = 1; w < 4; ++w) s += red[w][erow * RSTRIDE + cin];
        const float v = xin[(size_t)grow * ldxin + col] + s + bout[col];
        XL[grow * IN_ + col] = v;
        XLbf[grow * IN_ + col] = f2bf(v);
        dout[(size_t)grow * OUTROW + slot * IN_ + col] = v;
    }
}

// ---- Weight conversion: fp32 -> bf16, gate-permuted rows, fused biases ----
__global__ void conv_w(const float* Wih0, const float* Whh0, const float* bih0, const float* bhh0,
                       const float* Wih1, const float* Whh1, const float* bih1, const float* bhh1,
                       const float* Wout,
                       u16* W0c, float* b0p, u16* W1c, float* b1p, u16* Woutb)
{
    const int bid = blockIdx.x, tid = threadIdx.x;
    if (bid < 4096) {
        const int p = bid, rem = p & 63, G = rem >> 4, u = (p >> 6) * 16 + (rem & 15);
        const int src = G * H_ + u;
        for (int j = tid; j < IN_; j += 256)
            W0c[(size_t)p * 1152 + j] = f2bf(Wih0[(size_t)src * IN_ + j]);
        for (int j = tid; j < H_; j += 256)
            W0c[(size_t)p * 1152 + 128 + j] = f2bf(Whh0[(size_t)src * H_ + j]);
        if (tid == 0) b0p[p] = bih0[src] + bhh0[src];
    } else if (bid < 8192) {
        const int p = bid - 4096, rem = p & 63, G = rem >> 4, u = (p >> 6) * 16 + (rem & 15);
        const int src = G * H_ + u;
        for (int j = tid; j < H_; j += 256) {
            W1c[(size_t)p * 2048 + j]        = f2bf(Wih1[(size_t)src * H_ + j]);
            W1c[(size_t)p * 2048 + 1024 + j] = f2bf(Whh1[(size_t)src * H_ + j]);
        }
        if (tid == 0) b1p[p] = bih1[src] + bhh1[src];
    } else {
        const int r = bid - 8192; // 0..127
        for (int j = tid; j < H_; j += 256)
            Woutb[(size_t)r * H_ + j] = f2bf(Wout[(size_t)r * H_ + j]);
    }
}

// ---- Setup: zero states, x -> bf16 staging, x -> out[:, 0:16] copy ----
__global__ void setup_k(const float* __restrict__ x, u16* __restrict__ Xb,
                        u16* H0, u16* H1, float* c0, float* c1,
                        float* __restrict__ dout)
{
    const int i = blockIdx.x * 256 + threadIdx.x;  // < 512*16*128 = 1048576
    const float v = x[i];
    Xb[i] = f2bf(v);
    dout[(size_t)(i >> 11) * OUTROW + (i & 2047)] = v;
    if (i < B_ * H_) { H0[i] = 0; H1[i] = 0; c0[i] = 0.f; c1[i] = 0.f; }
}

extern "C" void kernel_launch(void* const* d_in, const int* in_sizes, int n_in,
                              void* d_out, int out_size, void* d_ws, size_t ws_size,
                              hipStream_t stream)
{
    const float* x    = (const float*)d_in[0];
    const float* Wih0 = (const float*)d_in[1];
    const float* Whh0 = (const float*)d_in[2];
    const float* bih0 = (const float*)d_in[3];
    const float* bhh0 = (const float*)d_in[4];
    const float* Wih1 = (const float*)d_in[5];
    const float* Whh1 = (const float*)d_in[6];
    const float* bih1 = (const float*)d_in[7];
    const float* bhh1 = (const float*)d_in[8];
    const float* Wout = (const float*)d_in[9];
    const float* bout = (const float*)d_in[10];
    float* dout = (float*)d_out;

    char* ws = (char*)d_ws;
    size_t off = 0;
    auto alloc = [&](size_t bytes) -> char* {
        char* p = ws + off; off += (bytes + 255) & ~(size_t)255; return p;
    };
    u16*  W0c   = (u16*)alloc(4096 * 1152 * 2);
    u16*  W1c   = (u16*)alloc(4096 * 2048 * 2);
    u16*  Woutb = (u16*)alloc(128 * 1024 * 2);
    float* b0p  = (float*)alloc(4096 * 4);
    float* b1p  = (float*)alloc(4096 * 4);
    u16*  Xb    = (u16*)alloc((size_t)B_ * L_ * IN_ * 2);
    u16*  H0b[2]; H0b[0] = (u16*)alloc((size_t)B_ * H_ * 2); H0b[1] = (u16*)alloc((size_t)B_ * H_ * 2);
    u16*  H1b[2]; H1b[0] = (u16*)alloc((size_t)B_ * H_ * 2); H1b[1] = (u16*)alloc((size_t)B_ * H_ * 2);
    float* c0   = (float*)alloc((size_t)B_ * H_ * 4);
    float* c1   = (float*)alloc((size_t)B_ * H_ * 4);
    float* XL   = (float*)alloc((size_t)B_ * IN_ * 4);
    u16*  XLbf  = (u16*)alloc((size_t)B_ * IN_ * 2);

    conv_w<<<8320, 256, 0, stream>>>(Wih0, Whh0, bih0, bhh0,
                                     Wih1, Whh1, bih1, bhh1, Wout,
                                     W0c, b0p, W1c, b1p, Woutb);
    setup_k<<<4096, 256, 0, stream>>>(x, Xb, H0b[0], H1b[0], c0, c1, dout);

    const dim3 cgrid(64, 8), pgrid(2, 8);
    int p = 0;
    for (int g = 0; g < 79; ++g) {   // 16 prompt + 63 rollout stack steps
        const u16* xpart; int ldx;
        if (g < 16) { xpart = Xb + g * IN_; ldx = L_ * IN_; }
        else        { xpart = XLbf;         ldx = IN_; }
        cell_gemm<<<cgrid, 256, 0, stream>>>(xpart, ldx, 2, H0b[p], H_, 16,
                                             W0c, IN_ + H_, b0p, c0, H0b[1 - p]);
        cell_gemm<<<cgrid, 256, 0, stream>>>(H0b[1 - p], H_, 16, H1b[p], H_, 16,
                                             W1c, 2 * H_, b1p, c1, H1b[1 - p]);
        if (g >= 15) {
            const int s = g - 15;            // 0..63 -> out slot 16+s
            const float* xin; int ldxin;
            if (s == 0) { xin = x + 15 * IN_; ldxin = L_ * IN_; }
            else        { xin = XL;           ldxin = IN_; }
            proj_gemm<<<pgrid, 256, 0, stream>>>(H1b[1 - p], Woutb, bout,
                                                 xin, ldxin, XL, XLbf, dout, 16 + s);
        }
        p ^= 1;
    }
}

// Round 7
// 5026.534 us; speedup vs baseline: 1.6550x; 1.0291x over previous
//
#include <hip/hip_runtime.h>

#define B_    512
#define L_    16
#define IN_   128
#define H_    1024
#define T_    64
#define OUTROW 10240   /* (L_+T_)*IN_ */

typedef __attribute__((ext_vector_type(8))) short bf8;
typedef __attribute__((ext_vector_type(4))) float f4;
typedef unsigned short u16;
typedef unsigned int   u32;

#define MFMA16(a, b, c) __builtin_amdgcn_mfma_f32_16x16x32_bf16(a, b, c, 0, 0, 0)

__device__ __forceinline__ u16 f2bf(float f) {
    u32 u = __builtin_bit_cast(u32, f);
    u32 r = (u + 0x7fffu + ((u >> 16) & 1u)) >> 16;
    return (u16)r;
}
__device__ __forceinline__ float sigm(float x) { return 1.f / (1.f + __expf(-x)); }
__device__ __forceinline__ float tanh_f(float x) {
    float ax = fabsf(x);
    float e = __expf(-2.f * ax);
    float t = (1.f - e) / (1.f + e);
    return x < 0.f ? -t : t;
}
__device__ __forceinline__ bf8 ld8(const u16* p) { return *(const bf8*)p; }

#define RSTRIDE 65   /* padded fp32 row stride in LDS reduction buffer */

// 16-MFMA pack on one fragment set (s-phase granularity)
#define MFMAP(AS, BS)                                                       \
  do {                                                                      \
    _Pragma("unroll")                                                       \
    for (int g_ = 0; g_ < 4; ++g_) {                                        \
      _Pragma("unroll")                                                     \
      for (int t_ = 0; t_ < 4; ++t_)                                        \
        acc[g_][t_] = MFMA16(AS[g_], BS[t_], acc[g_][t_]);                  \
    }                                                                       \
  } while (0)

// Load fragment set for phase PH of this wave's sequence.
// Phase -> (kt = ws + (PH>>1)*4, s = PH&1). A from concat(x-part, h-part).
#define LOADP_CELL(AS, BS, PH)                                              \
  do {                                                                      \
    const int kt_ = ws + (((PH) >> 1) << 2);                                \
    const int so_ = ((PH) & 1) * 32;                                        \
    const int kb_ = kt_ * 64 + so_;                                         \
    const bool ix_ = kt_ < nk1;                                             \
    const int ka_ = (ix_ ? kt_ : kt_ - nk1) * 64 + so_;                     \
    _Pragma("unroll")                                                       \
    for (int g_ = 0; g_ < 4; ++g_)                                          \
      AS[g_] = ld8((ix_ ? apx[g_] : aph[g_]) + ka_);                        \
    _Pragma("unroll")                                                       \
    for (int t_ = 0; t_ < 4; ++t_) BS[t_] = ld8(bp[t_] + kb_);              \
  } while (0)

#define LOADP_PROJ(AS, BS, PH)                                              \
  do {                                                                      \
    const int kt_ = ws + (((PH) >> 1) << 2);                                \
    const int k_  = kt_ * 64 + ((PH) & 1) * 32;                             \
    _Pragma("unroll")                                                       \
    for (int g_ = 0; g_ < 4; ++g_) AS[g_] = ld8(ap[g_] + k_);               \
    _Pragma("unroll")                                                       \
    for (int t_ = 0; t_ < 4; ++t_) BS[t_] = ld8(bp[t_] + k_);               \
  } while (0)

// ---- LSTM layer: 4-wave split-K GEMM (register-pipelined) + LDS reduction +
// fused cell epilogue. Block = 256 thr (4 waves); wave ws owns K-tiles
// kt === ws (mod 4). 1-D grid of 512 blocks with XCD-aware mapping:
// blocks dispatch round-robin over the 8 XCDs by linear id (%8), so
//   tn = (bid&7)*8 + ((bid>>3)&7),  tm = bid>>6
// pins each XCD to a fixed 8-value tn set -> per-XCD weight slice (~2 MB)
// stays L2-resident across all 79 steps (weights re-fetched from LLC only
// on the first step). B rows gate-permuted p = (u>>4)*64 + G*16 + (u&15):
// a block's 64-col group = gates i,f,g,o of units u = tn*16 + (0..15).
__global__ __launch_bounds__(256, 2) void cell_gemm(
    const u16* __restrict__ pA0, int ldA0, int nk1,
    const u16* __restrict__ pA1, int ldA1, int nk2,
    const u16* __restrict__ pB, int Ktot,
    const float* __restrict__ bias, float* __restrict__ Cst, u16* __restrict__ Hdst)
{
    __shared__ float red[4][64 * RSTRIDE];
    const int bid = blockIdx.x;
    const int tn = (bid & 7) * 8 + ((bid >> 3) & 7);
    const int tm = bid >> 6;
    const int tid = threadIdx.x;
    const int lane = tid & 63, ws = tid >> 6;
    const int l15 = lane & 15, qd = lane >> 4;

    f4 acc[4][4];
#pragma unroll
    for (int i = 0; i < 4; ++i)
#pragma unroll
        for (int j = 0; j < 4; ++j) acc[i][j] = (f4)(0.f);

    const u16* bp[4];
#pragma unroll
    for (int t = 0; t < 4; ++t)
        bp[t] = pB + (size_t)(tn * 64 + t * 16 + l15) * Ktot + qd * 8;
    const u16* apx[4];
    const u16* aph[4];
#pragma unroll
    for (int g = 0; g < 4; ++g) {
        apx[g] = pA0 + (size_t)(tm * 64 + g * 16 + l15) * ldA0 + qd * 8;
        aph[g] = pA1 + (size_t)(tm * 64 + g * 16 + l15) * ldA1 + qd * 8;
    }

    const int nk  = nk1 + nk2;
    const int myn = (nk - ws + 3) >> 2;     // tiles for this wave
    const int nph = myn * 2;                // s-phases (always even)

    bf8 A0[4], B0[4], A1[4], B1[4];
    LOADP_CELL(A0, B0, 0);
    for (int ph = 0; ph < nph; ph += 2) {
        LOADP_CELL(A1, B1, ph + 1);
        MFMAP(A0, B0);
        if (ph + 2 < nph) LOADP_CELL(A0, B0, ph + 2);
        MFMAP(A1, B1);
    }

    // dump partials to padded LDS
#pragma unroll
    for (int rg = 0; rg < 4; ++rg)
#pragma unroll
        for (int t = 0; t < 4; ++t)
#pragma unroll
            for (int r = 0; r < 4; ++r)
                red[ws][(rg * 16 + qd * 4 + r) * RSTRIDE + t * 16 + l15] = acc[rg][t][r];
    __syncthreads();

    // distributed epilogue: wave ws -> rows ws*16+(lane&15); units u15 = qd*4+j
    const int erow = ws * 16 + (lane & 15);
    const int grow = tm * 64 + erow;
#pragma unroll
    for (int j = 0; j < 4; ++j) {
        const int u15 = qd * 4 + j;
        float g4[4];
#pragma unroll
        for (int G = 0; G < 4; ++G) {
            float s = red[0][erow * RSTRIDE + G * 16 + u15];
#pragma unroll
            for (int w = 1; w < 4; ++w) s += red[w][erow * RSTRIDE + G * 16 + u15];
            g4[G] = s + bias[tn * 64 + G * 16 + u15];
        }
        const float I  = sigm(g4[0]);
        const float F  = sigm(g4[1]);
        const float Gg = tanh_f(g4[2]);
        const float O  = sigm(g4[3]);
        const size_t ix = (size_t)grow * H_ + tn * 16 + u15;
        const float cn = F * Cst[ix] + I * Gg;
        Cst[ix] = cn;
        Hdst[ix] = f2bf(O * tanh_f(cn));
    }
}

// ---- Output projection: 4-wave split-K (register-pipelined) + fused epilogue.
// 1-D grid of 16 blocks: tn = bid>>3, tm = bid&7 (Wout is only 0.25 MB, no
// XCD pinning needed). xl = xin + h1 @ Wout^T + b_out.
__global__ __launch_bounds__(256, 2) void proj_gemm(
    const u16* __restrict__ pA,   // H1 [512 x 1024] bf16
    const u16* __restrict__ pB,   // Woutb [128 x 1024] bf16
    const float* __restrict__ bout,
    const float* __restrict__ xin, int ldxin,
    float* __restrict__ XL, u16* __restrict__ XLbf,
    float* __restrict__ dout, int slot)
{
    __shared__ float red[4][64 * RSTRIDE];
    const int bid = blockIdx.x;
    const int tn = bid >> 3, tm = bid & 7;
    const int tid = threadIdx.x;
    const int lane = tid & 63, ws = tid >> 6;
    const int l15 = lane & 15, qd = lane >> 4;

    f4 acc[4][4];
#pragma unroll
    for (int i = 0; i < 4; ++i)
#pragma unroll
        for (int j = 0; j < 4; ++j) acc[i][j] = (f4)(0.f);

    const u16* bp[4];
#pragma unroll
    for (int t = 0; t < 4; ++t)
        bp[t] = pB + (size_t)(tn * 64 + t * 16 + l15) * H_ + qd * 8;
    const u16* ap[4];
#pragma unroll
    for (int g = 0; g < 4; ++g)
        ap[g] = pA + (size_t)(tm * 64 + g * 16 + l15) * H_ + qd * 8;

    const int nph = 8;   // 16 K-tiles / 4 waves * 2 s-phases
    bf8 A0[4], B0[4], A1[4], B1[4];
    LOADP_PROJ(A0, B0, 0);
    for (int ph = 0; ph < nph; ph += 2) {
        LOADP_PROJ(A1, B1, ph + 1);
        MFMAP(A0, B0);
        if (ph + 2 < nph) LOADP_PROJ(A0, B0, ph + 2);
        MFMAP(A1, B1);
    }

#pragma unroll
    for (int rg = 0; rg < 4; ++rg)
#pragma unroll
        for (int t = 0; t < 4; ++t)
#pragma unroll
            for (int r = 0; r < 4; ++r)
                red[ws][(rg * 16 + qd * 4 + r) * RSTRIDE + t * 16 + l15] = acc[rg][t][r];
    __syncthreads();

    const int erow = ws * 16 + (lane & 15);
    const int grow = tm * 64 + erow;
#pragma unroll
    for (int j = 0; j < 16; ++j) {
        const int cin = qd * 16 + j;
        const int col = tn * 64 + cin;
        float s = red[0][erow * RSTRIDE + cin];
#pragma unroll
        for (int w = 1; w < 4; ++w) s += red[w][erow * RSTRIDE + cin];
        const float v = xin[(size_t)grow * ldxin + col] + s + bout[col];
        XL[grow * IN_ + col] = v;
        XLbf[grow * IN_ + col] = f2bf(v);
        dout[(size_t)grow * OUTROW + slot * IN_ + col] = v;
    }
}

// ---- Weight conversion: fp32 -> bf16, gate-permuted rows, fused biases ----
__global__ void conv_w(const float* Wih0, const float* Whh0, const float* bih0, const float* bhh0,
                       const float* Wih1, const float* Whh1, const float* bih1, const float* bhh1,
                       const float* Wout,
                       u16* W0c, float* b0p, u16* W1c, float* b1p, u16* Woutb)
{
    const int bid = blockIdx.x, tid = threadIdx.x;
    if (bid < 4096) {
        const int p = bid, rem = p & 63, G = rem >> 4, u = (p >> 6) * 16 + (rem & 15);
        const int src = G * H_ + u;
        for (int j = tid; j < IN_; j += 256)
            W0c[(size_t)p * 1152 + j] = f2bf(Wih0[(size_t)src * IN_ + j]);
        for (int j = tid; j < H_; j += 256)
            W0c[(size_t)p * 1152 + 128 + j] = f2bf(Whh0[(size_t)src * H_ + j]);
        if (tid == 0) b0p[p] = bih0[src] + bhh0[src];
    } else if (bid < 8192) {
        const int p = bid - 4096, rem = p & 63, G = rem >> 4, u = (p >> 6) * 16 + (rem & 15);
        const int src = G * H_ + u;
        for (int j = tid; j < H_; j += 256) {
            W1c[(size_t)p * 2048 + j]        = f2bf(Wih1[(size_t)src * H_ + j]);
            W1c[(size_t)p * 2048 + 1024 + j] = f2bf(Whh1[(size_t)src * H_ + j]);
        }
        if (tid == 0) b1p[p] = bih1[src] + bhh1[src];
    } else {
        const int r = bid - 8192; // 0..127
        for (int j = tid; j < H_; j += 256)
            Woutb[(size_t)r * H_ + j] = f2bf(Wout[(size_t)r * H_ + j]);
    }
}

// ---- Setup: zero states, x -> bf16 staging, x -> out[:, 0:16] copy ----
__global__ void setup_k(const float* __restrict__ x, u16* __restrict__ Xb,
                        u16* H0, u16* H1, float* c0, float* c1,
                        float* __restrict__ dout)
{
    const int i = blockIdx.x * 256 + threadIdx.x;  // < 512*16*128 = 1048576
    const float v = x[i];
    Xb[i] = f2bf(v);
    dout[(size_t)(i >> 11) * OUTROW + (i & 2047)] = v;
    if (i < B_ * H_) { H0[i] = 0; H1[i] = 0; c0[i] = 0.f; c1[i] = 0.f; }
}

extern "C" void kernel_launch(void* const* d_in, const int* in_sizes, int n_in,
                              void* d_out, int out_size, void* d_ws, size_t ws_size,
                              hipStream_t stream)
{
    const float* x    = (const float*)d_in[0];
    const float* Wih0 = (const float*)d_in[1];
    const float* Whh0 = (const float*)d_in[2];
    const float* bih0 = (const float*)d_in[3];
    const float* bhh0 = (const float*)d_in[4];
    const float* Wih1 = (const float*)d_in[5];
    const float* Whh1 = (const float*)d_in[6];
    const float* bih1 = (const float*)d_in[7];
    const float* bhh1 = (const float*)d_in[8];
    const float* Wout = (const float*)d_in[9];
    const float* bout = (const float*)d_in[10];
    float* dout = (float*)d_out;

    char* ws = (char*)d_ws;
    size_t off = 0;
    auto alloc = [&](size_t bytes) -> char* {
        char* p = ws + off; off += (bytes + 255) & ~(size_t)255; return p;
    };
    u16*  W0c   = (u16*)alloc(4096 * 1152 * 2);
    u16*  W1c   = (u16*)alloc(4096 * 2048 * 2);
    u16*  Woutb = (u16*)alloc(128 * 1024 * 2);
    float* b0p  = (float*)alloc(4096 * 4);
    float* b1p  = (float*)alloc(4096 * 4);
    u16*  Xb    = (u16*)alloc((size_t)B_ * L_ * IN_ * 2);
    u16*  H0b[2]; H0b[0] = (u16*)alloc((size_t)B_ * H_ * 2); H0b[1] = (u16*)alloc((size_t)B_ * H_ * 2);
    u16*  H1b[2]; H1b[0] = (u16*)alloc((size_t)B_ * H_ * 2); H1b[1] = (u16*)alloc((size_t)B_ * H_ * 2);
    float* c0   = (float*)alloc((size_t)B_ * H_ * 4);
    float* c1   = (float*)alloc((size_t)B_ * H_ * 4);
    float* XL   = (float*)alloc((size_t)B_ * IN_ * 4);
    u16*  XLbf  = (u16*)alloc((size_t)B_ * IN_ * 2);

    conv_w<<<8320, 256, 0, stream>>>(Wih0, Whh0, bih0, bhh0,
                                     Wih1, Whh1, bih1, bhh1, Wout,
                                     W0c, b0p, W1c, b1p, Woutb);
    setup_k<<<4096, 256, 0, stream>>>(x, Xb, H0b[0], H1b[0], c0, c1, dout);

    int p = 0;
    for (int g = 0; g < 79; ++g) {   // 16 prompt + 63 rollout stack steps
        const u16* xpart; int ldx;
        if (g < 16) { xpart = Xb + g * IN_; ldx = L_ * IN_; }
        else        { xpart = XLbf;         ldx = IN_; }
        cell_gemm<<<512, 256, 0, stream>>>(xpart, ldx, 2, H0b[p], H_, 16,
                                           W0c, IN_ + H_, b0p, c0, H0b[1 - p]);
        cell_gemm<<<512, 256, 0, stream>>>(H0b[1 - p], H_, 16, H1b[p], H_, 16,
                                           W1c, 2 * H_, b1p, c1, H1b[1 - p]);
        if (g >= 15) {
            const int s = g - 15;            // 0..63 -> out slot 16+s
            const float* xin; int ldxin;
            if (s == 0) { xin = x + 15 * IN_; ldxin = L_ * IN_; }
            else        { xin = XL;           ldxin = IN_; }
            proj_gemm<<<16, 256, 0, stream>>>(H1b[1 - p], Woutb, bout,
                                              xin, ldxin, XL, XLbf, dout, 16 + s);
        }
        p ^= 1;
    }
}

// Round 8
// 4133.155 us; speedup vs baseline: 2.0127x; 1.2161x over previous
//
#include <hip/hip_runtime.h>

#define B_    512
#define L_    16
#define IN_   128
#define H_    1024
#define T_    64
#define OUTROW 10240   /* (L_+T_)*IN_ */

/* padded leading dims (elements) — +32B per row breaks L2 channel aliasing
   (power-of-2 row strides put all 16 lines of a fragment load on ONE channel) */
#define LDW0  1168   /* W0c rows (K=1152) */
#define LDW1  2064   /* W1c rows (K=2048) */
#define LDWO  1040   /* Woutb rows (K=1024) */
#define LDH   1040   /* H state rows (1024 cols used) */
#define LDC   1040   /* c state rows (fp32) */
#define LDX   2064   /* Xb rows (2048 cols used) */
#define LDXL  144    /* XL / XLbf rows (128 cols used) */

typedef __attribute__((ext_vector_type(8))) short bf8;
typedef __attribute__((ext_vector_type(4))) float f4;
typedef unsigned short u16;
typedef unsigned int   u32;

#define MFMA16(a, b, c) __builtin_amdgcn_mfma_f32_16x16x32_bf16(a, b, c, 0, 0, 0)

__device__ __forceinline__ u16 f2bf(float f) {
    u32 u = __builtin_bit_cast(u32, f);
    u32 r = (u + 0x7fffu + ((u >> 16) & 1u)) >> 16;
    return (u16)r;
}
__device__ __forceinline__ float sigm(float x) { return 1.f / (1.f + __expf(-x)); }
__device__ __forceinline__ float tanh_f(float x) {
    float ax = fabsf(x);
    float e = __expf(-2.f * ax);
    float t = (1.f - e) / (1.f + e);
    return x < 0.f ? -t : t;
}
__device__ __forceinline__ bf8 ld8(const u16* p) { return *(const bf8*)p; }

#define RSTRIDE 65   /* padded fp32 row stride in LDS reduction buffer */

// 16-MFMA pack on one fragment set (s-phase granularity)
#define MFMAP(AS, BS)                                                       \
  do {                                                                      \
    _Pragma("unroll")                                                       \
    for (int g_ = 0; g_ < 4; ++g_) {                                        \
      _Pragma("unroll")                                                     \
      for (int t_ = 0; t_ < 4; ++t_)                                        \
        acc[g_][t_] = MFMA16(AS[g_], BS[t_], acc[g_][t_]);                  \
    }                                                                       \
  } while (0)

// Load fragment set for phase PH of this wave's sequence.
// Phase -> (kt = ws + (PH>>1)*4, s = PH&1). A from concat(x-part, h-part).
#define LOADP_CELL(AS, BS, PH)                                              \
  do {                                                                      \
    const int kt_ = ws + (((PH) >> 1) << 2);                                \
    const int so_ = ((PH) & 1) * 32;                                        \
    const int kb_ = kt_ * 64 + so_;                                         \
    const bool ix_ = kt_ < nk1;                                             \
    const int ka_ = (ix_ ? kt_ : kt_ - nk1) * 64 + so_;                     \
    _Pragma("unroll")                                                       \
    for (int g_ = 0; g_ < 4; ++g_)                                          \
      AS[g_] = ld8((ix_ ? apx[g_] : aph[g_]) + ka_);                        \
    _Pragma("unroll")                                                       \
    for (int t_ = 0; t_ < 4; ++t_) BS[t_] = ld8(bp[t_] + kb_);              \
  } while (0)

#define LOADP_PROJ(AS, BS, PH)                                              \
  do {                                                                      \
    const int kt_ = ws + (((PH) >> 1) << 2);                                \
    const int k_  = kt_ * 64 + ((PH) & 1) * 32;                             \
    _Pragma("unroll")                                                       \
    for (int g_ = 0; g_ < 4; ++g_) AS[g_] = ld8(ap[g_] + k_);               \
    _Pragma("unroll")                                                       \
    for (int t_ = 0; t_ < 4; ++t_) BS[t_] = ld8(bp[t_] + k_);               \
  } while (0)

// ---- LSTM layer: 4-wave split-K GEMM (register-pipelined) + LDS reduction +
// fused cell epilogue. Block = 256 thr (4 waves); wave ws owns K-tiles
// kt === ws (mod 4). XCD-aware 1-D grid mapping (512 blocks):
//   tn = (bid&7)*8 + ((bid>>3)&7),  tm = bid>>6
// so the 8 tm-blocks sharing one tn weight slice land on one XCD (single LLC
// fetch per XCD per dispatch). All buffers use +32B-padded row strides to
// spread fragment-load lines across L2 channels. B rows gate-permuted
// p = (u>>4)*64 + G*16 + (u&15): block's 64-col group = gates i,f,g,o of
// units u = tn*16 + (0..15), all in-lane.
__global__ __launch_bounds__(256, 2) void cell_gemm(
    const u16* __restrict__ pA0, int ldA0, int nk1,
    const u16* __restrict__ pA1, int ldA1, int nk2,
    const u16* __restrict__ pB, int ldB,
    const float* __restrict__ bias, float* __restrict__ Cst, u16* __restrict__ Hdst)
{
    __shared__ float red[4][64 * RSTRIDE];
    const int bid = blockIdx.x;
    const int tn = (bid & 7) * 8 + ((bid >> 3) & 7);
    const int tm = bid >> 6;
    const int tid = threadIdx.x;
    const int lane = tid & 63, ws = tid >> 6;
    const int l15 = lane & 15, qd = lane >> 4;

    f4 acc[4][4];
#pragma unroll
    for (int i = 0; i < 4; ++i)
#pragma unroll
        for (int j = 0; j < 4; ++j) acc[i][j] = (f4)(0.f);

    const u16* bp[4];
#pragma unroll
    for (int t = 0; t < 4; ++t)
        bp[t] = pB + (size_t)(tn * 64 + t * 16 + l15) * ldB + qd * 8;
    const u16* apx[4];
    const u16* aph[4];
#pragma unroll
    for (int g = 0; g < 4; ++g) {
        apx[g] = pA0 + (size_t)(tm * 64 + g * 16 + l15) * ldA0 + qd * 8;
        aph[g] = pA1 + (size_t)(tm * 64 + g * 16 + l15) * ldA1 + qd * 8;
    }

    const int nk  = nk1 + nk2;
    const int myn = (nk - ws + 3) >> 2;     // tiles for this wave
    const int nph = myn * 2;                // s-phases (always even)

    bf8 A0[4], B0[4], A1[4], B1[4];
    LOADP_CELL(A0, B0, 0);
    for (int ph = 0; ph < nph; ph += 2) {
        LOADP_CELL(A1, B1, ph + 1);
        MFMAP(A0, B0);
        if (ph + 2 < nph) LOADP_CELL(A0, B0, ph + 2);
        MFMAP(A1, B1);
    }

    // dump partials to padded LDS
#pragma unroll
    for (int rg = 0; rg < 4; ++rg)
#pragma unroll
        for (int t = 0; t < 4; ++t)
#pragma unroll
            for (int r = 0; r < 4; ++r)
                red[ws][(rg * 16 + qd * 4 + r) * RSTRIDE + t * 16 + l15] = acc[rg][t][r];
    __syncthreads();

    // distributed epilogue: wave ws -> rows ws*16+(lane&15); units u15 = qd*4+j
    const int erow = ws * 16 + (lane & 15);
    const int grow = tm * 64 + erow;
#pragma unroll
    for (int j = 0; j < 4; ++j) {
        const int u15 = qd * 4 + j;
        float g4[4];
#pragma unroll
        for (int G = 0; G < 4; ++G) {
            float s = red[0][erow * RSTRIDE + G * 16 + u15];
#pragma unroll
            for (int w = 1; w < 4; ++w) s += red[w][erow * RSTRIDE + G * 16 + u15];
            g4[G] = s + bias[tn * 64 + G * 16 + u15];
        }
        const float I  = sigm(g4[0]);
        const float F  = sigm(g4[1]);
        const float Gg = tanh_f(g4[2]);
        const float O  = sigm(g4[3]);
        const size_t cx = (size_t)grow * LDC + tn * 16 + u15;
        const float cn = F * Cst[cx] + I * Gg;
        Cst[cx] = cn;
        Hdst[(size_t)grow * LDH + tn * 16 + u15] = f2bf(O * tanh_f(cn));
    }
}

// ---- Output projection: 4-wave split-K (register-pipelined) + fused epilogue.
// 1-D grid of 16 blocks: tn = bid>>3, tm = bid&7. xl = xin + h1 @ Wout^T + b_out.
__global__ __launch_bounds__(256, 2) void proj_gemm(
    const u16* __restrict__ pA,   // H1 [512 x LDH] bf16
    const u16* __restrict__ pB,   // Woutb [128 x LDWO] bf16
    const float* __restrict__ bout,
    const float* __restrict__ xin, int ldxin,
    float* __restrict__ XL, u16* __restrict__ XLbf,
    float* __restrict__ dout, int slot)
{
    __shared__ float red[4][64 * RSTRIDE];
    const int bid = blockIdx.x;
    const int tn = bid >> 3, tm = bid & 7;
    const int tid = threadIdx.x;
    const int lane = tid & 63, ws = tid >> 6;
    const int l15 = lane & 15, qd = lane >> 4;

    f4 acc[4][4];
#pragma unroll
    for (int i = 0; i < 4; ++i)
#pragma unroll
        for (int j = 0; j < 4; ++j) acc[i][j] = (f4)(0.f);

    const u16* bp[4];
#pragma unroll
    for (int t = 0; t < 4; ++t)
        bp[t] = pB + (size_t)(tn * 64 + t * 16 + l15) * LDWO + qd * 8;
    const u16* ap[4];
#pragma unroll
    for (int g = 0; g < 4; ++g)
        ap[g] = pA + (size_t)(tm * 64 + g * 16 + l15) * LDH + qd * 8;

    const int nph = 8;   // 16 K-tiles / 4 waves * 2 s-phases
    bf8 A0[4], B0[4], A1[4], B1[4];
    LOADP_PROJ(A0, B0, 0);
    for (int ph = 0; ph < nph; ph += 2) {
        LOADP_PROJ(A1, B1, ph + 1);
        MFMAP(A0, B0);
        if (ph + 2 < nph) LOADP_PROJ(A0, B0, ph + 2);
        MFMAP(A1, B1);
    }

#pragma unroll
    for (int rg = 0; rg < 4; ++rg)
#pragma unroll
        for (int t = 0; t < 4; ++t)
#pragma unroll
            for (int r = 0; r < 4; ++r)
                red[ws][(rg * 16 + qd * 4 + r) * RSTRIDE + t * 16 + l15] = acc[rg][t][r];
    __syncthreads();

    const int erow = ws * 16 + (lane & 15);
    const int grow = tm * 64 + erow;
#pragma unroll
    for (int j = 0; j < 16; ++j) {
        const int cin = qd * 16 + j;
        const int col = tn * 64 + cin;
        float s = red[0][erow * RSTRIDE + cin];
#pragma unroll
        for (int w = 1; w < 4; ++w) s += red[w][erow * RSTRIDE + cin];
        const float v = xin[(size_t)grow * ldxin + col] + s + bout[col];
        XL[grow * LDXL + col] = v;
        XLbf[grow * LDXL + col] = f2bf(v);
        dout[(size_t)grow * OUTROW + slot * IN_ + col] = v;
    }
}

// ---- Weight conversion: fp32 -> bf16, gate-permuted rows, padded strides,
// fused biases ----
__global__ void conv_w(const float* Wih0, const float* Whh0, const float* bih0, const float* bhh0,
                       const float* Wih1, const float* Whh1, const float* bih1, const float* bhh1,
                       const float* Wout,
                       u16* W0c, float* b0p, u16* W1c, float* b1p, u16* Woutb)
{
    const int bid = blockIdx.x, tid = threadIdx.x;
    if (bid < 4096) {
        const int p = bid, rem = p & 63, G = rem >> 4, u = (p >> 6) * 16 + (rem & 15);
        const int src = G * H_ + u;
        for (int j = tid; j < IN_; j += 256)
            W0c[(size_t)p * LDW0 + j] = f2bf(Wih0[(size_t)src * IN_ + j]);
        for (int j = tid; j < H_; j += 256)
            W0c[(size_t)p * LDW0 + 128 + j] = f2bf(Whh0[(size_t)src * H_ + j]);
        if (tid == 0) b0p[p] = bih0[src] + bhh0[src];
    } else if (bid < 8192) {
        const int p = bid - 4096, rem = p & 63, G = rem >> 4, u = (p >> 6) * 16 + (rem & 15);
        const int src = G * H_ + u;
        for (int j = tid; j < H_; j += 256) {
            W1c[(size_t)p * LDW1 + j]        = f2bf(Wih1[(size_t)src * H_ + j]);
            W1c[(size_t)p * LDW1 + 1024 + j] = f2bf(Whh1[(size_t)src * H_ + j]);
        }
        if (tid == 0) b1p[p] = bih1[src] + bhh1[src];
    } else {
        const int r = bid - 8192; // 0..127
        for (int j = tid; j < H_; j += 256)
            Woutb[(size_t)r * LDWO + j] = f2bf(Wout[(size_t)r * H_ + j]);
    }
}

// ---- Setup: zero states, x -> bf16 staging (padded), x -> out[:, 0:16] copy ----
__global__ void setup_k(const float* __restrict__ x, u16* __restrict__ Xb,
                        u16* H0, u16* H1, float* c0, float* c1,
                        float* __restrict__ dout)
{
    const int i = blockIdx.x * 256 + threadIdx.x;  // < 512*16*128 = 1048576
    const float v = x[i];
    Xb[(size_t)(i >> 11) * LDX + (i & 2047)] = f2bf(v);
    dout[(size_t)(i >> 11) * OUTROW + (i & 2047)] = v;
    if (i < B_ * H_) {
        const int r = i >> 10, c = i & 1023;
        H0[(size_t)r * LDH + c] = 0; H1[(size_t)r * LDH + c] = 0;
        c0[(size_t)r * LDC + c] = 0.f; c1[(size_t)r * LDC + c] = 0.f;
    }
}

extern "C" void kernel_launch(void* const* d_in, const int* in_sizes, int n_in,
                              void* d_out, int out_size, void* d_ws, size_t ws_size,
                              hipStream_t stream)
{
    const float* x    = (const float*)d_in[0];
    const float* Wih0 = (const float*)d_in[1];
    const float* Whh0 = (const float*)d_in[2];
    const float* bih0 = (const float*)d_in[3];
    const float* bhh0 = (const float*)d_in[4];
    const float* Wih1 = (const float*)d_in[5];
    const float* Whh1 = (const float*)d_in[6];
    const float* bih1 = (const float*)d_in[7];
    const float* bhh1 = (const float*)d_in[8];
    const float* Wout = (const float*)d_in[9];
    const float* bout = (const float*)d_in[10];
    float* dout = (float*)d_out;

    char* ws = (char*)d_ws;
    size_t off = 0;
    auto alloc = [&](size_t bytes) -> char* {
        char* p = ws + off; off += (bytes + 255) & ~(size_t)255; return p;
    };
    u16*  W0c   = (u16*)alloc((size_t)4096 * LDW0 * 2);
    u16*  W1c   = (u16*)alloc((size_t)4096 * LDW1 * 2);
    u16*  Woutb = (u16*)alloc((size_t)128 * LDWO * 2);
    float* b0p  = (float*)alloc(4096 * 4);
    float* b1p  = (float*)alloc(4096 * 4);
    u16*  Xb    = (u16*)alloc((size_t)B_ * LDX * 2);
    u16*  H0b[2]; H0b[0] = (u16*)alloc((size_t)B_ * LDH * 2); H0b[1] = (u16*)alloc((size_t)B_ * LDH * 2);
    u16*  H1b[2]; H1b[0] = (u16*)alloc((size_t)B_ * LDH * 2); H1b[1] = (u16*)alloc((size_t)B_ * LDH * 2);
    float* c0   = (float*)alloc((size_t)B_ * LDC * 4);
    float* c1   = (float*)alloc((size_t)B_ * LDC * 4);
    float* XL   = (float*)alloc((size_t)B_ * LDXL * 4);
    u16*  XLbf  = (u16*)alloc((size_t)B_ * LDXL * 2);

    conv_w<<<8320, 256, 0, stream>>>(Wih0, Whh0, bih0, bhh0,
                                     Wih1, Whh1, bih1, bhh1, Wout,
                                     W0c, b0p, W1c, b1p, Woutb);
    setup_k<<<4096, 256, 0, stream>>>(x, Xb, H0b[0], H1b[0], c0, c1, dout);

    int p = 0;
    for (int g = 0; g < 79; ++g) {   // 16 prompt + 63 rollout stack steps
        const u16* xpart; int ldx;
        if (g < 16) { xpart = Xb + g * IN_; ldx = LDX; }
        else        { xpart = XLbf;         ldx = LDXL; }
        cell_gemm<<<512, 256, 0, stream>>>(xpart, ldx, 2, H0b[p], LDH, 16,
                                           W0c, LDW0, b0p, c0, H0b[1 - p]);
        cell_gemm<<<512, 256, 0, stream>>>(H0b[1 - p], LDH, 16, H1b[p], LDH, 16,
                                           W1c, LDW1, b1p, c1, H1b[1 - p]);
        if (g >= 15) {
            const int s = g - 15;            // 0..63 -> out slot 16+s
            const float* xin; int ldxin;
            if (s == 0) { xin = x + 15 * IN_; ldxin = L_ * IN_; }
            else        { xin = XL;           ldxin = LDXL; }
            proj_gemm<<<16, 256, 0, stream>>>(H1b[1 - p], Woutb, bout,
                                              xin, ldxin, XL, XLbf, dout, 16 + s);
        }
        p ^= 1;
    }
}